// Round 1
// baseline (108.652 us; speedup 1.0000x reference)
//
#include <hip/hip_runtime.h>
#include <math.h>

// Sizes (fixed per reference)
#define NB 32
#define CC 256
#define CLSD 512
#define NG 64      // groups = C/4
#define HWPIX 4096 // 64*64
#define EPSV 1e-5f

__device__ __forceinline__ float waveReduceSum(float v) {
#pragma unroll
    for (int o = 32; o > 0; o >>= 1) v += __shfl_down(v, o, 64);
    return v;
}

// ---------------------------------------------------------------------------
// K1: per-(n,g) mean/var of X over 4 channels x HW = 16384 contiguous floats.
// grid: 2048 blocks (= n*64+g), 256 threads, float4 loads.
__global__ void k_stats1(const float* __restrict__ X,
                         float* __restrict__ mu1, float* __restrict__ inv1) {
    int b = blockIdx.x; // n*64+g ; group data contiguous at X + b*16384
    const float4* p = (const float4*)(X + (size_t)b * 16384);
    float s = 0.f, s2 = 0.f;
#pragma unroll
    for (int i = 0; i < 16; ++i) {
        float4 v = p[threadIdx.x + i * 256];
        s  += v.x + v.y + v.z + v.w;
        s2 += v.x * v.x + v.y * v.y + v.z * v.z + v.w * v.w;
    }
    __shared__ float ls[4], ls2[4];
    int lane = threadIdx.x & 63, wid = threadIdx.x >> 6;
    s = waveReduceSum(s);
    s2 = waveReduceSum(s2);
    if (lane == 0) { ls[wid] = s; ls2[wid] = s2; }
    __syncthreads();
    if (threadIdx.x == 0) {
        float S  = ls[0] + ls[1] + ls[2] + ls[3];
        float S2 = ls2[0] + ls2[1] + ls2[2] + ls2[3];
        float mu = S * (1.f / 16384.f);
        float var = S2 * (1.f / 16384.f) - mu * mu;
        mu1[b] = mu;
        inv1[b] = rsqrtf(var + EPSV);
    }
}

// ---------------------------------------------------------------------------
// K2: K[n,c] = elu(cls@wq.T + bq)+1 ; Q[n,c] = (elu(cls@wk.T + bk)+1)/16
// one wave per (n,c) output; 2048 blocks x 256 threads (4 waves each).
__global__ void k_kq(const float* __restrict__ cls,
                     const float* __restrict__ wq, const float* __restrict__ bq,
                     const float* __restrict__ wk, const float* __restrict__ bk,
                     float* __restrict__ Kb, float* __restrict__ Qb) {
    int w = blockIdx.x * 4 + (threadIdx.x >> 6); // 0..8191
    int lane = threadIdx.x & 63;
    int n = w >> 8, c = w & 255;
    const float* cp = cls + (size_t)n * CLSD;
    const float* qp = wq + (size_t)c * CLSD;
    const float* kp = wk + (size_t)c * CLSD;
    float aK = 0.f, aQ = 0.f;
#pragma unroll
    for (int i = 0; i < 8; ++i) {
        int kk = lane + i * 64;
        float cv = cp[kk];
        aK += cv * qp[kk];
        aQ += cv * kp[kk];
    }
    aK = waveReduceSum(aK);
    aQ = waveReduceSum(aQ);
    if (lane == 0) {
        float xk = aK + bq[c];
        float xq = aQ + bk[c];
        float Kv = (xk > 0.f ? xk : expf(xk) - 1.f) + 1.f;
        float Qv = ((xq > 0.f ? xq : expf(xq) - 1.f) + 1.f) * 0.0625f;
        Kb[w] = Kv;
        Qb[w] = Qv;
    }
}

// ---------------------------------------------------------------------------
// K3: A[n,c] = K*ln_w*inv1 ; B[n] = sum_c K*(ln_b - ln_w*inv1*mu1) ;
//     R[n,o] = sum_c conv_w[o,c]*Q[n,c]
// grid: 32 blocks (n), 256 threads (c or o)
__global__ void k_prep(const float* __restrict__ Kb, const float* __restrict__ Qb,
                       const float* __restrict__ ln_w, const float* __restrict__ ln_b,
                       const float* __restrict__ conv_w,
                       const float* __restrict__ mu1, const float* __restrict__ inv1,
                       float* __restrict__ A, float* __restrict__ B,
                       float* __restrict__ R) {
    int n = blockIdx.x, t = threadIdx.x;
    __shared__ float qs[256];
    __shared__ float red[4];
    float Kv = Kb[n * 256 + t];
    qs[t] = Qb[n * 256 + t];
    float iv = inv1[n * 64 + (t >> 2)];
    float mv = mu1[n * 64 + (t >> 2)];
    float lw = ln_w[t], lb = ln_b[t];
    A[n * 256 + t] = Kv * lw * iv;
    float termB = Kv * (lb - lw * iv * mv);
    int lane = t & 63, wid = t >> 6;
    float r = waveReduceSum(termB);
    if (lane == 0) red[wid] = r;
    __syncthreads(); // also fences qs[] writes
    if (t == 0) B[n] = red[0] + red[1] + red[2] + red[3];
    float acc = 0.f;
    const float* cw = conv_w + (size_t)t * 256;
#pragma unroll 4
    for (int c2 = 0; c2 < 256; ++c2) acc += cw[c2] * qs[c2];
    R[n * 256 + t] = acc;
}

// ---------------------------------------------------------------------------
// K4: s[n,p] = sum_c A[n,c]*X[n,c,p] + B[n]; also per-block partial sum/sumsq of s.
// grid: 512 blocks (n*16 + tile), 256 threads (one pixel each)
__global__ void k_spass(const float* __restrict__ X, const float* __restrict__ A,
                        const float* __restrict__ B, float* __restrict__ sbuf,
                        float* __restrict__ p1, float* __restrict__ p2) {
    int n = blockIdx.x >> 4, tile = blockIdx.x & 15;
    int pix = tile * 256 + threadIdx.x;
    __shared__ float as[256];
    as[threadIdx.x] = A[n * 256 + threadIdx.x];
    __syncthreads();
    const float* xp = X + (size_t)n * 256 * 4096 + pix;
    float acc = 0.f;
#pragma unroll 8
    for (int c = 0; c < 256; ++c) acc += as[c] * xp[(size_t)c * 4096];
    float s = acc + B[n];
    sbuf[n * 4096 + pix] = s;
    float r1v = waveReduceSum(s);
    float r2v = waveReduceSum(s * s);
    __shared__ float q1[4], q2[4];
    int lane = threadIdx.x & 63, wid = threadIdx.x >> 6;
    if (lane == 0) { q1[wid] = r1v; q2[wid] = r2v; }
    __syncthreads();
    if (threadIdx.x == 0) {
        p1[blockIdx.x] = q1[0] + q1[1] + q1[2] + q1[3];
        p2[blockIdx.x] = q2[0] + q2[1] + q2[2] + q2[3];
    }
}

// ---------------------------------------------------------------------------
// K5: alpha[n,o], beta[n,o] from s-moments + R + conv_b + gn params.
// grid: 32 blocks (n), 256 threads (o)
__global__ void k_ab(const float* __restrict__ p1, const float* __restrict__ p2,
                     const float* __restrict__ R, const float* __restrict__ conv_b,
                     const float* __restrict__ gn_w, const float* __restrict__ gn_b,
                     float* __restrict__ alpha, float* __restrict__ beta) {
    int n = blockIdx.x, t = threadIdx.x;
    __shared__ float Ms1s, Ms2s;
    if (t == 0) {
        float a = 0.f, b = 0.f;
#pragma unroll
        for (int i = 0; i < 16; ++i) { a += p1[n * 16 + i]; b += p2[n * 16 + i]; }
        Ms1s = a * (1.f / 4096.f);
        Ms2s = b * (1.f / 4096.f);
    }
    __syncthreads();
    float Ms1 = Ms1s, Ms2 = Ms2s;
    int g = t >> 2;
    float mR = 0.f, mR2 = 0.f, mRb = 0.f, mb = 0.f, mb2 = 0.f;
#pragma unroll
    for (int j = 0; j < 4; ++j) {
        float r = R[n * 256 + g * 4 + j];
        float b = conv_b[g * 4 + j];
        mR += r; mR2 += r * r; mRb += r * b; mb += b; mb2 += b * b;
    }
    mR *= 0.25f; mR2 *= 0.25f; mRb *= 0.25f; mb *= 0.25f; mb2 *= 0.25f;
    float mu = Ms1 * mR + mb;
    float var = Ms2 * mR2 + 2.f * Ms1 * mRb + mb2 - mu * mu;
    float iv = rsqrtf(var + EPSV);
    float r = R[n * 256 + t];
    alpha[n * 256 + t] = r * iv * gn_w[t];
    beta[n * 256 + t] = (conv_b[t] - mu) * iv * gn_w[t] + gn_b[t];
}

// ---------------------------------------------------------------------------
// K6: out = s*alpha + beta + X  (float4 over 33.5M elements)
// grid: 32768 blocks x 256 threads
__global__ void k_final(const float* __restrict__ X, const float* __restrict__ sbuf,
                        const float* __restrict__ alpha, const float* __restrict__ beta,
                        float* __restrict__ out) {
    size_t idx4 = (size_t)blockIdx.x * 256 + threadIdx.x;
    size_t e = idx4 * 4;
    int n = (int)(e >> 20);          // 256*4096 = 1,048,576 elems per n
    int rem = (int)(e & 1048575);
    int o = rem >> 12;
    int pix = rem & 4095;
    float4 x = ((const float4*)X)[idx4];
    float4 s = *(const float4*)(sbuf + n * 4096 + pix);
    float a = alpha[n * 256 + o], b = beta[n * 256 + o];
    float4 r;
    r.x = fmaf(s.x, a, b) + x.x;
    r.y = fmaf(s.y, a, b) + x.y;
    r.z = fmaf(s.z, a, b) + x.z;
    r.w = fmaf(s.w, a, b) + x.w;
    ((float4*)out)[idx4] = r;
}

// ---------------------------------------------------------------------------
extern "C" void kernel_launch(void* const* d_in, const int* in_sizes, int n_in,
                              void* d_out, int out_size, void* d_ws, size_t ws_size,
                              hipStream_t stream) {
    const float* X      = (const float*)d_in[0];
    const float* cls    = (const float*)d_in[1];
    const float* ln_w   = (const float*)d_in[2];
    const float* ln_b   = (const float*)d_in[3];
    const float* wq     = (const float*)d_in[4];
    const float* bq     = (const float*)d_in[5];
    const float* wk     = (const float*)d_in[6];
    const float* bk     = (const float*)d_in[7];
    const float* conv_w = (const float*)d_in[8];
    const float* conv_b = (const float*)d_in[9];
    const float* gn_w   = (const float*)d_in[10];
    const float* gn_b   = (const float*)d_in[11];

    float* ws = (float*)d_ws;
    float* mu1   = ws;            // 2048
    float* inv1  = ws + 2048;     // 2048
    float* Kb    = ws + 4096;     // 8192
    float* Qb    = ws + 12288;    // 8192
    float* A     = ws + 20480;    // 8192
    float* B     = ws + 28672;    // 32
    float* R     = ws + 28704;    // 8192
    float* p1    = ws + 36896;    // 512
    float* p2    = ws + 37408;    // 512
    float* alpha = ws + 37920;    // 8192
    float* beta  = ws + 46112;    // 8192
    float* sbuf  = ws + 65536;    // 131072 (16B-aligned offset)

    k_stats1<<<2048, 256, 0, stream>>>(X, mu1, inv1);
    k_kq<<<2048, 256, 0, stream>>>(cls, wq, bq, wk, bk, Kb, Qb);
    k_prep<<<32, 256, 0, stream>>>(Kb, Qb, ln_w, ln_b, conv_w, mu1, inv1, A, B, R);
    k_spass<<<512, 256, 0, stream>>>(X, A, B, sbuf, p1, p2);
    k_ab<<<32, 256, 0, stream>>>(p1, p2, R, conv_b, gn_w, gn_b, alpha, beta);
    k_final<<<32768, 256, 0, stream>>>(X, sbuf, alpha, beta, (float*)d_out);
}

// Round 2
// 94.976 us; speedup vs baseline: 1.1440x; 1.1440x over previous
//
#include <hip/hip_runtime.h>
#include <math.h>

#define EPSV 1e-5f

typedef float f4v __attribute__((ext_vector_type(4)));

__device__ __forceinline__ float waveReduceSum(float v) {
#pragma unroll
    for (int o = 32; o > 0; o >>= 1) v += __shfl_down(v, o, 64);
    return v;
}

// ---------------------------------------------------------------------------
// K1: K[n,c] = elu(cls@wq.T + bq)+1 ; Q[n,c] = (elu(cls@wk.T + bk)+1)/16
//     Kw[n,c] = K * ln_w[c]
// one wave per (n,c); 2048 blocks x 256 threads (4 waves each).
__global__ void k_kq(const float* __restrict__ cls,
                     const float* __restrict__ wq, const float* __restrict__ bq,
                     const float* __restrict__ wk, const float* __restrict__ bk,
                     const float* __restrict__ ln_w,
                     float* __restrict__ Kb, float* __restrict__ Qb,
                     float* __restrict__ Kw) {
    int w = blockIdx.x * 4 + (threadIdx.x >> 6); // 0..8191
    int lane = threadIdx.x & 63;
    int n = w >> 8, c = w & 255;
    const float* cp = cls + (size_t)n * 512;
    const float* qp = wq + (size_t)c * 512;
    const float* kp = wk + (size_t)c * 512;
    float aK = 0.f, aQ = 0.f;
#pragma unroll
    for (int i = 0; i < 8; ++i) {
        int kk = lane + i * 64;
        float cv = cp[kk];
        aK += cv * qp[kk];
        aQ += cv * kp[kk];
    }
    aK = waveReduceSum(aK);
    aQ = waveReduceSum(aQ);
    if (lane == 0) {
        float xk = aK + bq[c];
        float xq = aQ + bk[c];
        float Kv = (xk > 0.f ? xk : expf(xk) - 1.f) + 1.f;
        float Qv = ((xq > 0.f ? xq : expf(xq) - 1.f) + 1.f) * 0.0625f;
        Kb[w] = Kv;
        Qb[w] = Qv;
        Kw[w] = Kv * ln_w[c];
    }
}

// ---------------------------------------------------------------------------
// K2 (pass1): single read of X producing
//   W[n,g,p]  = sum_{c in g} Kw[n,c] * X[n,c,p]          (33.5 MB)
//   Sp/S2p[block,g] = per-tile partial sum / sumsq of X over group channels
// grid: 512 = n*16+tile; block 512 threads (8 waves). Wave w owns groups
// 8w..8w+8 (channels 32w..32w+32). Each wave covers the tile's 256 pixels
// as 64 lanes x float4.
__global__ void __launch_bounds__(512) k_pass1(
        const float* __restrict__ X, const float* __restrict__ Kw,
        float* __restrict__ W, float* __restrict__ Sp, float* __restrict__ S2p) {
    int n = blockIdx.x >> 4, tile = blockIdx.x & 15;
    int wv = threadIdx.x >> 6, lane = threadIdx.x & 63;
    __shared__ float kws[256];
    if (threadIdx.x < 256) kws[threadIdx.x] = Kw[n * 256 + threadIdx.x];
    __syncthreads();
    int pix = tile * 256 + lane * 4;
    const float* xb = X + ((size_t)n * 256 << 12) + pix;
#pragma unroll
    for (int go = 0; go < 8; ++go) {
        int g = wv * 8 + go;
        int c0 = g * 4;
        float ax = 0.f, ay = 0.f, az = 0.f, aw = 0.f;
        float s = 0.f, s2 = 0.f;
#pragma unroll
        for (int j = 0; j < 4; ++j) {
            float4 v = *(const float4*)(xb + ((size_t)(c0 + j) << 12));
            float kv = kws[c0 + j];
            ax += kv * v.x; ay += kv * v.y; az += kv * v.z; aw += kv * v.w;
            s  += v.x + v.y + v.z + v.w;
            s2 += v.x * v.x + v.y * v.y + v.z * v.z + v.w * v.w;
        }
        float4 acc = {ax, ay, az, aw};
        *(float4*)(W + ((size_t)(n * 64 + g) << 12) + pix) = acc;
        s = waveReduceSum(s);
        s2 = waveReduceSum(s2);
        if (lane == 0) {
            Sp[blockIdx.x * 64 + g] = s;
            S2p[blockIdx.x * 64 + g] = s2;
        }
    }
}

// ---------------------------------------------------------------------------
// K3: per-(n,g) stats reduce -> inv1; B[n]; R[n,o] = conv_w @ Q
// grid 32 (n), 256 threads
__global__ void k_prep2(const float* __restrict__ Sp, const float* __restrict__ S2p,
                        const float* __restrict__ Kb, const float* __restrict__ Qb,
                        const float* __restrict__ ln_w, const float* __restrict__ ln_b,
                        const float* __restrict__ conv_w,
                        float* __restrict__ inv1, float* __restrict__ B,
                        float* __restrict__ R) {
    int n = blockIdx.x, t = threadIdx.x;
    __shared__ float ivs[64], mus[64], qs[256], red[4];
    qs[t] = Qb[n * 256 + t];
    if (t < 64) {
        float S = 0.f, S2 = 0.f;
#pragma unroll
        for (int tl = 0; tl < 16; ++tl) {
            S  += Sp[(n * 16 + tl) * 64 + t];
            S2 += S2p[(n * 16 + tl) * 64 + t];
        }
        float mu = S * (1.f / 16384.f);
        float var = S2 * (1.f / 16384.f) - mu * mu;
        float iv = rsqrtf(var + EPSV);
        mus[t] = mu; ivs[t] = iv;
        inv1[n * 64 + t] = iv;
    }
    __syncthreads();
    float Kv = Kb[n * 256 + t];
    float termB = Kv * (ln_b[t] - ln_w[t] * ivs[t >> 2] * mus[t >> 2]);
    int lane = t & 63, wid = t >> 6;
    float r = waveReduceSum(termB);
    if (lane == 0) red[wid] = r;
    __syncthreads();
    if (t == 0) B[n] = red[0] + red[1] + red[2] + red[3];
    float acc = 0.f;
    const float* cw = conv_w + (size_t)t * 256;
#pragma unroll 4
    for (int c2 = 0; c2 < 256; ++c2) acc += cw[c2] * qs[c2];
    R[n * 256 + t] = acc;
}

// ---------------------------------------------------------------------------
// K4 (pass3): s[n,p] = sum_g inv_g * W[n,g,p] + B[n]; block partial moments.
// grid 128 = n*4+tile; 256 threads; thread handles one float4 (4 pixels).
__global__ void k_pass3(const float* __restrict__ W, const float* __restrict__ inv1,
                        const float* __restrict__ B, float* __restrict__ sbuf,
                        float* __restrict__ p1, float* __restrict__ p2) {
    int n = blockIdx.x >> 2, tile = blockIdx.x & 3;
    int t = threadIdx.x;
    __shared__ float ivs[64];
    __shared__ float q1[4], q2[4];
    if (t < 64) ivs[t] = inv1[n * 64 + t];
    __syncthreads();
    int pix = tile * 1024 + t * 4;
    const float* wb = W + ((size_t)n * 64 << 12) + pix;
    float Bn = B[n];
    float sx = Bn, sy = Bn, sz = Bn, sw = Bn;
#pragma unroll 8
    for (int g = 0; g < 64; ++g) {
        float4 v = *(const float4*)(wb + ((size_t)g << 12));
        float iv = ivs[g];
        sx += iv * v.x; sy += iv * v.y; sz += iv * v.z; sw += iv * v.w;
    }
    float4 s4 = {sx, sy, sz, sw};
    *(float4*)(sbuf + n * 4096 + pix) = s4;
    float r1 = sx + sy + sz + sw;
    float r2 = sx * sx + sy * sy + sz * sz + sw * sw;
    r1 = waveReduceSum(r1);
    r2 = waveReduceSum(r2);
    int lane = t & 63, wid = t >> 6;
    if (lane == 0) { q1[wid] = r1; q2[wid] = r2; }
    __syncthreads();
    if (t == 0) {
        p1[blockIdx.x] = q1[0] + q1[1] + q1[2] + q1[3];
        p2[blockIdx.x] = q2[0] + q2[1] + q2[2] + q2[3];
    }
}

// ---------------------------------------------------------------------------
// K5: alpha/beta from s-moments + R + conv_b + gn params. grid 32, 256 thr.
__global__ void k_ab(const float* __restrict__ p1, const float* __restrict__ p2,
                     const float* __restrict__ R, const float* __restrict__ conv_b,
                     const float* __restrict__ gn_w, const float* __restrict__ gn_b,
                     float* __restrict__ alpha, float* __restrict__ beta) {
    int n = blockIdx.x, t = threadIdx.x;
    __shared__ float Ms1s, Ms2s;
    if (t == 0) {
        float a = 0.f, b = 0.f;
#pragma unroll
        for (int i = 0; i < 4; ++i) { a += p1[n * 4 + i]; b += p2[n * 4 + i]; }
        Ms1s = a * (1.f / 4096.f);
        Ms2s = b * (1.f / 4096.f);
    }
    __syncthreads();
    float Ms1 = Ms1s, Ms2 = Ms2s;
    int g = t >> 2;
    float mR = 0.f, mR2 = 0.f, mRb = 0.f, mb = 0.f, mb2 = 0.f;
#pragma unroll
    for (int j = 0; j < 4; ++j) {
        float r = R[n * 256 + g * 4 + j];
        float b = conv_b[g * 4 + j];
        mR += r; mR2 += r * r; mRb += r * b; mb += b; mb2 += b * b;
    }
    mR *= 0.25f; mR2 *= 0.25f; mRb *= 0.25f; mb *= 0.25f; mb2 *= 0.25f;
    float mu = Ms1 * mR + mb;
    float var = Ms2 * mR2 + 2.f * Ms1 * mRb + mb2 - mu * mu;
    float iv = rsqrtf(var + EPSV);
    float r = R[n * 256 + t];
    alpha[n * 256 + t] = r * iv * gn_w[t];
    beta[n * 256 + t] = (conv_b[t] - mu) * iv * gn_w[t] + gn_b[t];
}

// ---------------------------------------------------------------------------
// K6: out = s*alpha + beta + X  (float4, nontemporal store)
// grid: 32768 blocks x 256 threads
__global__ void k_final(const float* __restrict__ X, const float* __restrict__ sbuf,
                        const float* __restrict__ alpha, const float* __restrict__ beta,
                        float* __restrict__ out) {
    size_t idx4 = (size_t)blockIdx.x * 256 + threadIdx.x;
    size_t e = idx4 * 4;
    int n = (int)(e >> 20);          // 256*4096 elems per n
    int rem = (int)(e & 1048575);
    int o = rem >> 12;
    int pix = rem & 4095;
    float4 x = ((const float4*)X)[idx4];
    float4 s = *(const float4*)(sbuf + n * 4096 + pix);
    float a = alpha[n * 256 + o], b = beta[n * 256 + o];
    f4v r;
    r.x = fmaf(s.x, a, b) + x.x;
    r.y = fmaf(s.y, a, b) + x.y;
    r.z = fmaf(s.z, a, b) + x.z;
    r.w = fmaf(s.w, a, b) + x.w;
    __builtin_nontemporal_store(r, (f4v*)out + idx4);
}

// ---------------------------------------------------------------------------
extern "C" void kernel_launch(void* const* d_in, const int* in_sizes, int n_in,
                              void* d_out, int out_size, void* d_ws, size_t ws_size,
                              hipStream_t stream) {
    const float* X      = (const float*)d_in[0];
    const float* cls    = (const float*)d_in[1];
    const float* ln_w   = (const float*)d_in[2];
    const float* ln_b   = (const float*)d_in[3];
    const float* wq     = (const float*)d_in[4];
    const float* bq     = (const float*)d_in[5];
    const float* wk     = (const float*)d_in[6];
    const float* bk     = (const float*)d_in[7];
    const float* conv_w = (const float*)d_in[8];
    const float* conv_b = (const float*)d_in[9];
    const float* gn_w   = (const float*)d_in[10];
    const float* gn_b   = (const float*)d_in[11];

    float* ws = (float*)d_ws;
    float* Kb    = ws;              // 8192
    float* Qb    = ws + 8192;       // 8192
    float* Kw    = ws + 16384;      // 8192
    float* Sp    = ws + 24576;      // 32768 (512 blocks x 64 groups)
    float* S2p   = ws + 57344;      // 32768
    float* inv1  = ws + 90112;      // 2048
    float* B     = ws + 92160;      // 32
    float* R     = ws + 92192;      // 8192
    float* p1    = ws + 100384;     // 128
    float* p2    = ws + 100512;     // 128
    float* alpha = ws + 100640;     // 8192
    float* beta  = ws + 108832;     // 8192
    float* sbuf  = ws + 131072;     // 131072 (32*4096)
    float* W     = ws + 262144;     // 8,388,608 (32*64*4096) = 33.5 MB

    k_kq<<<2048, 256, 0, stream>>>(cls, wq, bq, wk, bk, ln_w, Kb, Qb, Kw);
    k_pass1<<<512, 512, 0, stream>>>(X, Kw, W, Sp, S2p);
    k_prep2<<<32, 256, 0, stream>>>(Sp, S2p, Kb, Qb, ln_w, ln_b, conv_w, inv1, B, R);
    k_pass3<<<128, 256, 0, stream>>>(W, inv1, B, sbuf, p1, p2);
    k_ab<<<32, 256, 0, stream>>>(p1, p2, R, conv_b, gn_w, gn_b, alpha, beta);
    k_final<<<32768, 256, 0, stream>>>(X, sbuf, alpha, beta, (float*)d_out);
}